// Round 15
// baseline (51.461 us; speedup 1.0000x reference)
//
#include <hip/hip_runtime.h>
#include <hip/hip_bf16.h>

#define NROWS 8192
#define DCOLS 256
#define NTILES 2080   // 64*65/2 upper-triangle 128x128 tiles
constexpr float EPSV = 1e-6f;
constexpr float FP8_SCALE = 16.0f;
constexpr float GRAM_FIX = 2.0f / (FP8_SCALE * FP8_SCALE);

typedef __attribute__((ext_vector_type(4))) float f32x4;
typedef __attribute__((ext_vector_type(2))) long long ll2;

__device__ __forceinline__ void async16(void* lds, const void* g) {
    __builtin_amdgcn_global_load_lds(
        (const __attribute__((address_space(1))) void*)g,
        (__attribute__((address_space(3))) void*)lds, 16, 0, 0);
}

// ---------------- K12: row norms + per-block colsum partials (1024 blocks x 8 rows) ----------------
__global__ void k12_fused(const float* __restrict__ in, float* __restrict__ inv,
                          float* __restrict__ part) {
    int t = threadIdx.x, lane = t & 63, wave = t >> 6;
    int r0 = blockIdx.x * 8;
    __shared__ float cs[4][256];
    float4 acc4 = {0.f, 0.f, 0.f, 0.f};
    #pragma unroll
    for (int rr = 0; rr < 2; ++rr) {
        int row = r0 + wave * 2 + rr;
        float4 v = *reinterpret_cast<const float4*>(&in[row * DCOLS + lane * 4]);
        float s = v.x * v.x + v.y * v.y + v.z * v.z + v.w * v.w;
        #pragma unroll
        for (int o = 1; o < 64; o <<= 1) s += __shfl_xor(s, o);
        float iv = 1.0f / (sqrtf(s) + EPSV);
        if (lane == 0) inv[row] = iv;
        acc4.x += v.x * iv; acc4.y += v.y * iv; acc4.z += v.z * iv; acc4.w += v.w * iv;
    }
    *reinterpret_cast<float4*>(&cs[wave][lane * 4]) = acc4;
    __syncthreads();
    part[blockIdx.x * 256 + t] = cs[0][t] + cs[1][t] + cs[2][t] + cs[3][t];
}

// ---------------- KMID: reduce 1024 partial rows -> 16 ----------------
__global__ void kmid(const float* __restrict__ part, float* __restrict__ part2) {
    int t = threadIdx.x;
    float m = 0.f;
    #pragma unroll 8
    for (int i = 0; i < 64; ++i) m += part[(blockIdx.x * 64 + i) * 256 + t];
    part2[blockIdx.x * 256 + t] = m;
}

// ---------------- K3: colmean; center; write PACKED fp8 (x16); sq_norms (1024 blocks) ----------------
// Packed row layout (256B/row): byte(k) = (k>>6)*64 + (((k&31)>>3)<<4) + ((k>>5)&1)*8 + (k&7)
__global__ void k3_center(const float* __restrict__ in, const float* __restrict__ inv,
                          const float* __restrict__ part2,
                          unsigned char* __restrict__ cf8, float* __restrict__ sqn) {
    int t = threadIdx.x, lane = t & 63, wave = t >> 6;
    int r0 = blockIdx.x * 8;
    __shared__ float cm[256];
    float m = 0.f;
    #pragma unroll
    for (int i = 0; i < 16; ++i) m += part2[i * 256 + t];
    cm[t] = m * (1.0f / NROWS);
    __syncthreads();
    float4 m4 = *reinterpret_cast<const float4*>(&cm[lane * 4]);
    int k0 = lane * 4;
    int s4 = k0 >> 6, kp = k0 & 63, h = kp >> 5, kpp = kp & 31;
    int pos = s4 * 64 + ((kpp >> 3) << 4) + h * 8 + (kpp & 7);
    #pragma unroll
    for (int rr = 0; rr < 2; ++rr) {
        int row = r0 + wave * 2 + rr;
        float iv = inv[row];
        float4 v = *reinterpret_cast<const float4*>(&in[row * DCOLS + k0]);
        float4 cv = {v.x * iv - m4.x, v.y * iv - m4.y, v.z * iv - m4.z, v.w * iv - m4.w};
        int pk = __builtin_amdgcn_cvt_pk_fp8_f32(cv.x * FP8_SCALE, cv.y * FP8_SCALE, 0, false);
        pk = __builtin_amdgcn_cvt_pk_fp8_f32(cv.z * FP8_SCALE, cv.w * FP8_SCALE, pk, true);
        *reinterpret_cast<int*>(&cf8[row * DCOLS + pos]) = pk;
        float s = cv.x * cv.x + cv.y * cv.y + cv.z * cv.z + cv.w * cv.w;
        #pragma unroll
        for (int o = 1; o < 64; o <<= 1) s += __shfl_xor(s, o);
        if (lane == 0) sqn[row] = s;
    }
}

// ---------------- K4: 128x128 fp8 tile, 8 waves (64x32), FULL-K single stage ----------------
// A,B panels (128 x 256B each) staged once; ONE barrier; 4 K-slices barrier-free.
// LDS[r][granule g] = src[r][g ^ (r&15)]; read granule ((s*4+y)^rl) — r13-verified math.
__global__ __launch_bounds__(512, 4) void k4_dist(const unsigned char* __restrict__ cf8,
                                                  const float* __restrict__ sqn,
                                                  float* __restrict__ partial) {
    __shared__ unsigned char As[128 * 256];   // 32KB
    __shared__ unsigned char Bs[128 * 256];   // 32KB
    __shared__ float sqA[128], sqB[128];
    __shared__ float red8[8];

    int bid = blockIdx.x;
    int idx = (bid & 7) * (NTILES / 8) + (bid >> 3);   // XCD swizzle, 2080%8==0
    int q = (int)((sqrtf(8.0f * (float)idx + 1.0f) - 1.0f) * 0.5f);
    while ((q + 1) * (q + 2) / 2 <= idx) ++q;
    while (q * (q + 1) / 2 > idx) --q;
    int p = idx - q * (q + 1) / 2;

    int brow = p * 128, bcol = q * 128;
    int t = threadIdx.x, lane = t & 63, wave = t >> 6;
    int wr = wave >> 2, wc = wave & 3;            // 2x4 wave grid: 64x32 out each
    int rl = lane & 15, y = lane >> 4;
    int Rw = wave * 16;

    const char* gbase = (const char*)cf8;
    size_t aRowOff = (size_t)(brow + Rw + y) * 256;
    size_t bRowOff = (size_t)(bcol + Rw + y) * 256;
    int g0 = rl ^ y;

    // prologue: stage both panels + sq slices, one drain
    #pragma unroll
    for (int c = 0; c < 4; ++c) {
        int gsw = (g0 ^ (4 * c)) << 4;
        async16(&As[(Rw + 4 * c) * 256], gbase + aRowOff + c * 1024 + gsw);
        async16(&Bs[(Rw + 4 * c) * 256], gbase + bRowOff + c * 1024 + gsw);
    }
    if (t < 128) sqA[t] = sqn[brow + t];
    else if (t < 256) sqB[t - 128] = sqn[bcol + t - 128];
    __syncthreads();

    f32x4 acc[4][2] = {};
    #pragma unroll
    for (int s = 0; s < 4; ++s) {
        int gs = ((s * 4 + y) ^ rl) << 4;
        ll2 a[4], b[2];
        #pragma unroll
        for (int m = 0; m < 4; ++m)
            a[m] = *reinterpret_cast<const ll2*>(&As[(wr * 64 + m * 16 + rl) * 256 + gs]);
        #pragma unroll
        for (int n = 0; n < 2; ++n)
            b[n] = *reinterpret_cast<const ll2*>(&Bs[(wc * 32 + n * 16 + rl) * 256 + gs]);
        #pragma unroll
        for (int m = 0; m < 4; ++m)
            #pragma unroll
            for (int n = 0; n < 2; ++n) {
                acc[m][n] = __builtin_amdgcn_mfma_f32_16x16x32_fp8_fp8(a[m].x, b[n].x, acc[m][n], 0, 0, 0);
                acc[m][n] = __builtin_amdgcn_mfma_f32_16x16x32_fp8_fp8(a[m].y, b[n].y, acc[m][n], 0, 0, 0);
            }
    }

    // epilogue
    float local = 0.0f;
    #pragma unroll
    for (int n = 0; n < 2; ++n) {
        float sj = sqB[wc * 32 + n * 16 + rl];
        #pragma unroll
        for (int m = 0; m < 4; ++m) {
            int i0 = wr * 64 + m * 16 + y * 4;
            #pragma unroll
            for (int r = 0; r < 4; ++r) {
                float sq = sqA[i0 + r] + sj - GRAM_FIX * acc[m][n][r];
                local += (sq > 0.0f) ? sqrtf(sq) : 0.0f;
            }
        }
    }
    #pragma unroll
    for (int o = 1; o < 64; o <<= 1) local += __shfl_xor(local, o);
    if (lane == 0) red8[wave] = local;
    __syncthreads();
    if (t == 0) {
        float w = (p == q) ? 1.0f : 2.0f;
        float s8 = 0.f;
        #pragma unroll
        for (int i = 0; i < 8; ++i) s8 += red8[i];
        partial[idx] = w * s8;
    }
}

// ---------------- K5: final scalar ----------------
__global__ void k5_final(const float* __restrict__ sqn, const float* __restrict__ partial,
                         float* __restrict__ out) {
    int t = threadIdx.x;
    int lane = t & 63, wave = t >> 6;
    float s = 0.0f;
    for (int r = t; r < NROWS; r += 1024) s += sqn[r];
    double ds = 0.0;
    for (int r = t; r < NTILES; r += 1024) ds += (double)partial[r];
    #pragma unroll
    for (int o = 1; o < 64; o <<= 1) { s += __shfl_xor(s, o); ds += __shfl_xor(ds, o); }
    __shared__ float redf[16];
    __shared__ double redd[16];
    if (lane == 0) { redf[wave] = s; redd[wave] = ds; }
    __syncthreads();
    if (t == 0) {
        float sumsq = 0.f; double sd = 0.0;
        #pragma unroll
        for (int i = 0; i < 16; ++i) { sumsq += redf[i]; sd += redd[i]; }
        double md = sd / ((double)NROWS * (double)NROWS);
        out[0] = (float)DCOLS / sumsq + (float)log(md);
    }
}

extern "C" void kernel_launch(void* const* d_in, const int* in_sizes, int n_in,
                              void* d_out, int out_size, void* d_ws, size_t ws_size,
                              hipStream_t stream) {
    const float* emb = (const float*)d_in[0];
    float* out = (float*)d_out;
    char* ws = (char*)d_ws;

    float*  inv     = (float*)ws;                    // 8192 f32
    float*  sqn     = (float*)(ws + 36864);          // 8192 f32
    float*  partial = (float*)(ws + 69632);          // 2080 f32
    float*  part    = (float*)(ws + 81920);          // 1024*256 f32 = 1MB
    float*  part2   = (float*)(ws + 81920 + 1048576);// 16*256 f32
    unsigned char* cf8 = (unsigned char*)(ws + 81920 + 1048576 + 16384); // 2MB packed fp8

    k12_fused <<<1024, 256, 0, stream>>>(emb, inv, part);
    kmid      <<<16, 256, 0, stream>>>(part, part2);
    k3_center <<<1024, 256, 0, stream>>>(emb, inv, part2, cf8, sqn);
    k4_dist   <<<NTILES, 512, 0, stream>>>(cf8, sqn, partial);
    k5_final  <<<1, 1024, 0, stream>>>(sqn, partial, out);
}